// Round 11
// baseline (759.439 us; speedup 1.0000x reference)
//
#include <hip/hip_runtime.h>

typedef _Float16 f16;
typedef f16 f16x8 __attribute__((ext_vector_type(8)));
typedef f16 f16x4 __attribute__((ext_vector_type(4)));
typedef float f32x4 __attribute__((ext_vector_type(4)));

#define B_ 64
#define C_ 512
#define X2D_ELEMS ((size_t)134217728)  // 64*512*64*64
#define CHAIN_PITCH 1104               // chain: [b][col][512] f16

// (i,j) -> chain column, or -1
__device__ __forceinline__ int col_of(int i, int j) {
    const int d = j - i;
    if (d < 0) return -1;
    if (d <= 15) return 64 * d - (d * (d - 1)) / 2 + i;
    if (d >= 17 && d <= 31 && (d & 1) && !(i & 1)) {
        const int v = (d - 17) >> 1;
        return 904 + 24 * v - (v * (v - 1)) / 2 + (i >> 1);
    }
    if (d >= 35 && !((d - 35) & 3) && !(i & 3)) {
        const int v = (d - 35) >> 2;
        return 1068 + 8 * v - (v * (v - 1)) / 2 + (i >> 2);
    }
    return -1;
}

// ---------------------------------------------------------------------------
// m_rep=2 conv body: wave w owns co [q*128 + w*32, +32) = 2 m-tiles; nf=4
// col-fragments (G*Lout cols, masked). S: swizzled [rows][512], proven layout.
// Each bf LDS read feeds 2 MFMAs (acc[m][nf]).
// ---------------------------------------------------------------------------
template<int K, int TAPS>
__device__ __forceinline__
void conv_body(const f16* S, const f16* __restrict__ Wl,
               const float* __restrict__ bias, f16* __restrict__ chain,
               int b0, int q, int cb_out, int Lin, int Lout, int G)
{
    const int lane = threadIdx.x & 63, w = threadIdx.x >> 6;
    const int colq = lane & 15, kg = lane >> 4;
    const int cobase = q * 128 + w * 32;
    const f16* wp0 = Wl + (size_t)(cobase + colq) * K + (kg << 3);
    const f16* wp1 = wp0 + (size_t)16 * K;

    int vg[4], vl[4], row0[4]; bool val[4];
    #pragma unroll
    for (int nf = 0; nf < 4; nf++) {
        const int v = nf * 16 + colq;
        vg[nf] = v / Lout; vl[nf] = v - vg[nf] * Lout;
        val[nf] = vg[nf] < G;
        row0[nf] = val[nf] ? vg[nf] * Lin + vl[nf] : 0;
    }

    f32x4 acc0[4] = {}, acc1[4] = {};
    #pragma unroll 4
    for (int k0 = 0; k0 < K; k0 += 32) {
        const f16x8 af0 = *(const f16x8*)(wp0 + k0);
        const f16x8 af1 = *(const f16x8*)(wp1 + k0);
        const int t = (TAPS == 2 && k0 >= 512) ? 1 : 0;
        const int cch = ((k0 & 511) >> 3) + kg;
        #pragma unroll
        for (int nf = 0; nf < 4; nf++) {
            const int r = row0[nf] + t;
            const f16x8 bf = *(const f16x8*)&S[(r << 9) + ((cch ^ (r & 7)) << 3)];
            acc0[nf] = __builtin_amdgcn_mfma_f32_16x16x32_f16(af0, bf, acc0[nf], 0, 0, 0);
            acc1[nf] = __builtin_amdgcn_mfma_f32_16x16x32_f16(af1, bf, acc1[nf], 0, 0, 0);
        }
    }

    const int co0 = cobase + (kg << 2);
    const float4 bb0 = *(const float4*)&bias[co0];
    const float4 bb1 = *(const float4*)&bias[co0 + 16];
    #pragma unroll
    for (int nf = 0; nf < 4; nf++) {
        if (!val[nf]) continue;
        const size_t base = (((size_t)(b0 + vg[nf]) * CHAIN_PITCH + cb_out + vl[nf]) << 9);
        f16x4 h0, h1;
        #pragma unroll
        for (int j = 0; j < 4; j++) {
            h0[j] = (f16)fmaxf(acc0[nf][j] + ((const float*)&bb0)[j], 0.0f);
            h1[j] = (f16)fmaxf(acc1[nf][j] + ((const float*)&bb1)[j], 0.0f);
        }
        *(f16x4*)&chain[base + co0] = h0;
        *(f16x4*)&chain[base + co0 + 16] = h1;
    }
}

// ---------------------------------------------------------------------------
// k=2 conv kernel, optional fused maxpool on the staging path.
// Grid: (64/G, 4) — x = b-group (b-affine XCD), y = q co-slice of 128.
//   POOL=0: stage rows g*Lin+l from chain[cb_in + l]
//   POOL=1: cb_in = pre-pool layer (length 2*Lin+1); stage pooled+relu rows,
//           q==0 block also writes pool layer to chain at cb_pool.
// ---------------------------------------------------------------------------
template<int POOL>
__global__ __launch_bounds__(256, 2)
void conv_k2(const f16* __restrict__ chainr, int cb_in,
             const f16* __restrict__ Wl, const float* __restrict__ bias,
             f16* __restrict__ chain, int cb_pool, int cb_out,
             int Lin, int Lout, int G)
{
    __shared__ __align__(16) f16 S[64 * 512];
    const int lane = threadIdx.x & 63, wv = threadIdx.x >> 6;
    const int b0 = blockIdx.x * G, q = blockIdx.y;
    const int rows = G * Lin;

    for (int r = wv; r < rows; r += 4) {
        const int g = r / Lin, l = r - g * Lin;
        f16x8 o;
        if (POOL) {
            const f16* src = chainr +
                (((size_t)(b0 + g) * CHAIN_PITCH + cb_in + 2 * l) << 9) + (lane << 3);
            const f16x8 s0 = *(const f16x8*)(src);
            const f16x8 s1 = *(const f16x8*)(src + 512);
            const f16x8 s2 = *(const f16x8*)(src + 1024);
            #pragma unroll
            for (int j = 0; j < 8; j++)
                o[j] = (f16)fmaxf(fmaxf((float)s0[j], (float)s1[j]),
                                  fmaxf((float)s2[j], 0.0f));
            if (q == 0)
                *(f16x8*)&chain[(((size_t)(b0 + g) * CHAIN_PITCH + cb_pool + l) << 9)
                                + (lane << 3)] = o;
        } else {
            o = *(const f16x8*)(chainr +
                (((size_t)(b0 + g) * CHAIN_PITCH + cb_in + l) << 9) + (lane << 3));
        }
        *(f16x8*)&S[(r << 9) + ((lane ^ (r & 7)) << 3)] = o;
    }
    __syncthreads();
    conv_body<1024, 2>(S, Wl, bias, chain, b0, q, cb_out, Lin, Lout, G);
}

// layer 0: k=1 conv from fp32 x; grid (64, 4) — x = b, y = q
__global__ __launch_bounds__(256, 2)
void conv_first(const float* __restrict__ x, const f16* __restrict__ Wf,
                const float* __restrict__ b1, f16* __restrict__ chain)
{
    __shared__ __align__(16) f16 S[64 * 512];
    const int tid = threadIdx.x;
    const int b = blockIdx.x, q = blockIdx.y;
    #pragma unroll 4
    for (int p = 0; p < 32; p++) {
        const int ci = p * 16 + (tid >> 4), l0 = (tid & 15) << 2;
        const float4 v = *(const float4*)&x[(((size_t)b * C_ + ci) << 6) + l0];
        #pragma unroll
        for (int j = 0; j < 4; j++) {
            const int r = l0 + j;
            S[(r << 9) + (((ci >> 3) ^ (r & 7)) << 3) + (ci & 7)] =
                (f16)((const float*)&v)[j];
        }
    }
    __syncthreads();
    conv_body<512, 1>(S, Wf, b1, chain, b, q, 0, 64, 64, 1);
}

// prep: mask + weights fp32 -> f16 [co][t*512+ci]
__global__ void prep_all(const float* __restrict__ w1, const float* __restrict__ w2,
                         f16* __restrict__ Wf, float* __restrict__ maskp)
{
    const unsigned idx = blockIdx.x * 256 + threadIdx.x;
    if (idx < 4096u)
        maskp[idx] = (col_of(idx >> 6, idx & 63) >= 0) ? 1.0f : 0.0f;
    if (idx < 262144u) {
        Wf[idx] = (f16)w1[idx];
    } else if (idx < 30u * 262144u) {
        const unsigned r = idx - 262144u;
        const int k2 = r >> 18;
        const unsigned rem = r & 262143u;
        const int co = rem >> 9, ci = rem & 511;
        const float2 v = *(const float2*)&w2[((((size_t)k2 << 9) + co) << 10) + (ci << 1)];
        f16* base = Wf + 262144 + ((size_t)k2 << 19) + ((size_t)co << 10);
        base[ci] = (f16)v.x;
        base[512 + ci] = (f16)v.y;
    }
}

// assemble (proven): block=(i, b); swizzled LDS stage; coalesced x2d write
__global__ __launch_bounds__(256)
void assemble3(const f16* __restrict__ chain, float* __restrict__ x2d)
{
    __shared__ __align__(16) f16 J[64 * 512];
    const int tid = threadIdx.x, lane = tid & 63, wv = tid >> 6;
    const int i = blockIdx.x, b = blockIdx.y;

    for (int j = wv; j < 64; j += 4) {
        const int col = col_of(i, j);
        f16x8 v = {0, 0, 0, 0, 0, 0, 0, 0};
        if (col >= 0)
            v = *(const f16x8*)(chain + (((size_t)b * CHAIN_PITCH + col) << 9) + (lane << 3));
        *(f16x8*)&J[(j << 9) + ((lane ^ (j & 7)) << 3)] = v;
    }
    __syncthreads();

    const int jq = tid & 15, c0 = tid >> 4;
    float* dst0 = x2d + (((size_t)b * C_) << 12) + (i << 6) + (jq << 2);
    for (int ct = 0; ct < 32; ct++) {
        const int c = c0 + (ct << 4);
        const int cj = c >> 3;
        float4 o;
        #pragma unroll
        for (int jj = 0; jj < 4; jj++) {
            const int j = (jq << 2) + jj;
            ((float*)&o)[jj] = (float)J[(j << 9) + ((cj ^ (j & 7)) << 3) + (c & 7)];
        }
        *(float4*)(dst0 + ((size_t)c << 12)) = o;
    }
}

extern "C" void kernel_launch(void* const* d_in, const int* in_sizes, int n_in,
                              void* d_out, int out_size, void* d_ws, size_t ws_size,
                              hipStream_t stream)
{
    const float* x  = (const float*)d_in[0];
    const float* w1 = (const float*)d_in[1];
    const float* b1 = (const float*)d_in[2];
    const float* w2 = (const float*)d_in[3];
    const float* b2 = (const float*)d_in[4];
    float* x2d   = (float*)d_out;
    float* maskp = x2d + X2D_ELEMS;

    // chain (72.3 MB) in d_ws; f16 weights (31 MB) in the x2d region —
    // fully overwritten by assemble3 after weights are dead.
    f16* chain = (f16*)d_ws;
    f16* Wf    = (f16*)x2d;

    prep_all<<<(30 * 262144) / 256, 256, 0, stream>>>(w1, w2, Wf, maskp);

    // layer 0: k=1 conv from fp32 x
    conv_first<<<dim3(64, 4), 256, 0, stream>>>(x, Wf, b1, chain);

    // level 0: 15 k=2 convs (64 -> 49), G=1, grid (64, 4)
    int L = 64, cb = 64, prev = 0, k2 = 0;
    for (int i = 0; i < 15; i++) {
        conv_k2<0><<<dim3(64, 4), 256, 0, stream>>>(
            chain, prev, Wf + 262144 + (size_t)k2 * 524288, b2 + (size_t)k2 * C_,
            chain, 0, cb, L, L - 1, 1);
        k2++; prev = cb; cb += L - 1; L--;
    }
    // L=49, prev=855, cb=904

    // level 1: fused pool(49->24)+conv, then 6 convs; G=2, grid (32, 4)
    conv_k2<1><<<dim3(32, 4), 256, 0, stream>>>(
        chain, prev, Wf + 262144 + (size_t)k2 * 524288, b2 + (size_t)k2 * C_,
        chain, 904, 928, 24, 23, 2);
    k2++; L = 23; prev = 928; cb = 951;
    for (int i = 0; i < 6; i++) {
        conv_k2<0><<<dim3(32, 4), 256, 0, stream>>>(
            chain, prev, Wf + 262144 + (size_t)k2 * 524288, b2 + (size_t)k2 * C_,
            chain, 0, cb, L, L - 1, 2);
        k2++; prev = cb; cb += L - 1; L--;
    }
    // L=17, prev=1051, cb=1068

    // level 2: fused pool(17->8)+conv, then 6 convs; G=8, grid (8, 4)
    conv_k2<1><<<dim3(8, 4), 256, 0, stream>>>(
        chain, prev, Wf + 262144 + (size_t)k2 * 524288, b2 + (size_t)k2 * C_,
        chain, 1068, 1076, 8, 7, 8);
    k2++; L = 7; prev = 1076; cb = 1083;
    for (int i = 0; i < 6; i++) {
        conv_k2<0><<<dim3(8, 4), 256, 0, stream>>>(
            chain, prev, Wf + 262144 + (size_t)k2 * 524288, b2 + (size_t)k2 * C_,
            chain, 0, cb, L, L - 1, 8);
        k2++; prev = cb; cb += L - 1; L--;
    }

    assemble3<<<dim3(64, B_), 256, 0, stream>>>(chain, x2d);
}

// Round 12
// 750.323 us; speedup vs baseline: 1.0121x; 1.0121x over previous
//
#include <hip/hip_runtime.h>

typedef _Float16 f16;
typedef f16 f16x8 __attribute__((ext_vector_type(8)));
typedef f16 f16x4 __attribute__((ext_vector_type(4)));
typedef float f32x4 __attribute__((ext_vector_type(4)));

#define B_ 64
#define C_ 512
#define X2D_ELEMS ((size_t)134217728)  // 64*512*64*64
#define CHAIN_PITCH 1104               // chain: [b][col][512] f16

// (i,j) -> chain column, or -1
__device__ __forceinline__ int col_of(int i, int j) {
    const int d = j - i;
    if (d < 0) return -1;
    if (d <= 15) return 64 * d - (d * (d - 1)) / 2 + i;
    if (d >= 17 && d <= 31 && (d & 1) && !(i & 1)) {
        const int v = (d - 17) >> 1;
        return 904 + 24 * v - (v * (v - 1)) / 2 + (i >> 1);
    }
    if (d >= 35 && !((d - 35) & 3) && !(i & 3)) {
        const int v = (d - 35) >> 2;
        return 1068 + 8 * v - (v * (v - 1)) / 2 + (i >> 2);
    }
    return -1;
}

// ---------------------------------------------------------------------------
// conv body, 2x2 wave grid: block = 64 co x 64 n (G*Lout cols), 4 waves as
// (wm, wn) in 2x2; each wave 32 co x 32 n -> m_rep=2, nf=2, acc 2x2.
// Each pair of LDS bf reads feeds 4 MFMAs (half the LDS traffic of R10).
// S: swizzled [rows][512 ci] (proven layout). Weights [co][t*512+ci] f16.
// ---------------------------------------------------------------------------
template<int K, int TAPS>
__device__ __forceinline__
void conv_body22(const f16* S, const f16* __restrict__ Wl,
                 const float* __restrict__ bias, f16* __restrict__ chain,
                 int b0, int m0, int cb_out, int Lin, int Lout, int G)
{
    const int lane = threadIdx.x & 63, wv = threadIdx.x >> 6;
    const int wm = wv >> 1, wn = wv & 1;
    const int colq = lane & 15, kg = lane >> 4;
    const f16* wp0 = Wl + (size_t)(m0 + wm * 32 + colq) * K + (kg << 3);
    const f16* wp1 = wp0 + (size_t)16 * K;

    int row0[2], vg[2], vl[2]; bool val[2];
    #pragma unroll
    for (int nf = 0; nf < 2; nf++) {
        const int v = wn * 32 + nf * 16 + colq;
        vg[nf] = v / Lout; vl[nf] = v - vg[nf] * Lout;
        val[nf] = vg[nf] < G;
        row0[nf] = val[nf] ? vg[nf] * Lin + vl[nf] : 0;
    }

    f32x4 acc00 = {}, acc01 = {}, acc10 = {}, acc11 = {};
    #pragma unroll 4
    for (int k0 = 0; k0 < K; k0 += 32) {
        const f16x8 af0 = *(const f16x8*)(wp0 + k0);
        const f16x8 af1 = *(const f16x8*)(wp1 + k0);
        const int t = (TAPS == 2 && k0 >= 512) ? 1 : 0;
        const int cch = ((k0 & 511) >> 3) + kg;
        const int r0 = row0[0] + t, r1 = row0[1] + t;
        const f16x8 bf0 = *(const f16x8*)&S[(r0 << 9) + ((cch ^ (r0 & 7)) << 3)];
        const f16x8 bf1 = *(const f16x8*)&S[(r1 << 9) + ((cch ^ (r1 & 7)) << 3)];
        acc00 = __builtin_amdgcn_mfma_f32_16x16x32_f16(af0, bf0, acc00, 0, 0, 0);
        acc10 = __builtin_amdgcn_mfma_f32_16x16x32_f16(af1, bf0, acc10, 0, 0, 0);
        acc01 = __builtin_amdgcn_mfma_f32_16x16x32_f16(af0, bf1, acc01, 0, 0, 0);
        acc11 = __builtin_amdgcn_mfma_f32_16x16x32_f16(af1, bf1, acc11, 0, 0, 0);
    }

    const int co0 = m0 + wm * 32 + (kg << 2);
    const float4 bb0 = *(const float4*)&bias[co0];
    const float4 bb1 = *(const float4*)&bias[co0 + 16];
    #pragma unroll
    for (int nf = 0; nf < 2; nf++) {
        if (!val[nf]) continue;
        const size_t base = (((size_t)(b0 + vg[nf]) * CHAIN_PITCH + cb_out + vl[nf]) << 9);
        const f32x4 a0 = nf ? acc01 : acc00;
        const f32x4 a1 = nf ? acc11 : acc10;
        f16x4 h0, h1;
        #pragma unroll
        for (int j = 0; j < 4; j++) {
            h0[j] = (f16)fmaxf(a0[j] + ((const float*)&bb0)[j], 0.0f);
            h1[j] = (f16)fmaxf(a1[j] + ((const float*)&bb1)[j], 0.0f);
        }
        *(f16x4*)&chain[base + co0] = h0;
        *(f16x4*)&chain[base + co0 + 16] = h1;
    }
}

// assemble unit (proven logic): stage 64 j-rows for row i of batch b into
// swizzled LDS, then fully-coalesced float4 x2d write for all 512 c.
__device__ __forceinline__
void assemble_unit(f16* S, const f16* __restrict__ chain,
                   float* __restrict__ x2d, int i, int b)
{
    const int tid = threadIdx.x, lane = tid & 63, wv = tid >> 6;
    for (int j = wv; j < 64; j += 4) {
        const int col = col_of(i, j);
        f16x8 v = {0, 0, 0, 0, 0, 0, 0, 0};
        if (col >= 0)
            v = *(const f16x8*)(chain + (((size_t)b * CHAIN_PITCH + col) << 9) + (lane << 3));
        *(f16x8*)&S[(j << 9) + ((lane ^ (j & 7)) << 3)] = v;
    }
    __syncthreads();
    const int jq = tid & 15, c0 = tid >> 4;
    float* dst0 = x2d + (((size_t)b * C_) << 12) + (i << 6) + (jq << 2);
    for (int ct = 0; ct < 32; ct++) {
        const int c = c0 + (ct << 4);
        const int cj = c >> 3;
        float4 o;
        #pragma unroll
        for (int jj = 0; jj < 4; jj++) {
            const int j = (jq << 2) + jj;
            ((float*)&o)[jj] = (float)S[(j << 9) + ((cj ^ (j & 7)) << 3) + (c & 7)];
        }
        *(float4*)(dst0 + ((size_t)c << 12)) = o;
    }
}

// ---------------------------------------------------------------------------
// k=2 conv kernel; optional fused maxpool staging; optional assemble-helper
// blocks (blockIdx.y >= nbg) that finish x2d rows whose diagonals are done
// (b >= 4 only: first 31 MB of x2d holds Wf scratch until the chain ends).
// Grid: (8 m-slices, nbg b-groups [+ helper rows]).
// ---------------------------------------------------------------------------
template<int POOL>
__global__ __launch_bounds__(256, 2)
void conv_k2(int cb_in, const f16* __restrict__ Wl,
             const float* __restrict__ bias, f16* __restrict__ chain,
             int cb_pool, int cb_out, int Lin, int Lout, int G, int nbg,
             float* __restrict__ x2d, int au_base, int au_tot, int row_base)
{
    __shared__ __align__(16) f16 S[64 * 512];
    if ((int)blockIdx.y >= nbg) {
        const int u = au_base + ((int)blockIdx.y - nbg) * 8 + (int)blockIdx.x;
        if (u >= au_tot) return;
        assemble_unit(S, chain, x2d, row_base + u / 60, 4 + u % 60);
        return;
    }
    const int lane = threadIdx.x & 63, wv = threadIdx.x >> 6;
    const int b0 = blockIdx.y * G, m0 = blockIdx.x * 64;
    const int rows = G * Lin;

    for (int r = wv; r < rows; r += 4) {
        const int g = r / Lin, l = r - g * Lin;
        f16x8 o;
        if (POOL) {
            const f16* src = chain +
                (((size_t)(b0 + g) * CHAIN_PITCH + cb_in + 2 * l) << 9) + (lane << 3);
            const f16x8 s0 = *(const f16x8*)(src);
            const f16x8 s1 = *(const f16x8*)(src + 512);
            const f16x8 s2 = *(const f16x8*)(src + 1024);
            #pragma unroll
            for (int j = 0; j < 8; j++)
                o[j] = (f16)fmaxf(fmaxf((float)s0[j], (float)s1[j]),
                                  fmaxf((float)s2[j], 0.0f));
            if (blockIdx.x == 0)
                *(f16x8*)&chain[(((size_t)(b0 + g) * CHAIN_PITCH + cb_pool + l) << 9)
                                + (lane << 3)] = o;
        } else {
            o = *(const f16x8*)(chain +
                (((size_t)(b0 + g) * CHAIN_PITCH + cb_in + l) << 9) + (lane << 3));
        }
        *(f16x8*)&S[(r << 9) + ((lane ^ (r & 7)) << 3)] = o;
    }
    __syncthreads();
    conv_body22<1024, 2>(S, Wl, bias, chain, b0, m0, cb_out, Lin, Lout, G);
}

// layer 0: k=1 conv from fp32 x; grid (8, 64) — x = m-slice, y = b
__global__ __launch_bounds__(256, 2)
void conv_first(const float* __restrict__ x, const f16* __restrict__ Wf,
                const float* __restrict__ b1, f16* __restrict__ chain)
{
    __shared__ __align__(16) f16 S[64 * 512];
    const int tid = threadIdx.x;
    const int b = blockIdx.y, m0 = blockIdx.x * 64;
    #pragma unroll 4
    for (int p = 0; p < 32; p++) {
        const int ci = p * 16 + (tid >> 4), l0 = (tid & 15) << 2;
        const float4 v = *(const float4*)&x[(((size_t)b * C_ + ci) << 6) + l0];
        #pragma unroll
        for (int j = 0; j < 4; j++) {
            const int r = l0 + j;
            S[(r << 9) + (((ci >> 3) ^ (r & 7)) << 3) + (ci & 7)] =
                (f16)((const float*)&v)[j];
        }
    }
    __syncthreads();
    conv_body22<512, 1>(S, Wf, b1, chain, b, m0, 0, 64, 64, 1);
}

// prep: mask + weights fp32 -> f16 [co][t*512+ci]
__global__ void prep_all(const float* __restrict__ w1, const float* __restrict__ w2,
                         f16* __restrict__ Wf, float* __restrict__ maskp)
{
    const unsigned idx = blockIdx.x * 256 + threadIdx.x;
    if (idx < 4096u)
        maskp[idx] = (col_of(idx >> 6, idx & 63) >= 0) ? 1.0f : 0.0f;
    if (idx < 262144u) {
        Wf[idx] = (f16)w1[idx];
    } else if (idx < 30u * 262144u) {
        const unsigned r = idx - 262144u;
        const int k2 = r >> 18;
        const unsigned rem = r & 262143u;
        const int co = rem >> 9, ci = rem & 511;
        const float2 v = *(const float2*)&w2[((((size_t)k2 << 9) + co) << 10) + (ci << 1)];
        f16* base = Wf + 262144 + ((size_t)k2 << 19) + ((size_t)co << 10);
        base[ci] = (f16)v.x;
        base[512 + ci] = (f16)v.y;
    }
}

// final assemble: rows 0..32 all b (2112 units) + rows 33..63 b<4 (124 units)
__global__ __launch_bounds__(256)
void assemble_fin(const f16* __restrict__ chain, float* __restrict__ x2d)
{
    __shared__ __align__(16) f16 S[64 * 512];
    const int u = blockIdx.x;
    int i, b;
    if (u < 2112) { i = u >> 6; b = u & 63; }
    else { const int v = u - 2112; i = 33 + (v >> 2); b = v & 3; }
    assemble_unit(S, chain, x2d, i, b);
}

extern "C" void kernel_launch(void* const* d_in, const int* in_sizes, int n_in,
                              void* d_out, int out_size, void* d_ws, size_t ws_size,
                              hipStream_t stream)
{
    const float* x  = (const float*)d_in[0];
    const float* w1 = (const float*)d_in[1];
    const float* b1 = (const float*)d_in[2];
    const float* w2 = (const float*)d_in[3];
    const float* b2 = (const float*)d_in[4];
    float* x2d   = (float*)d_out;
    float* maskp = x2d + X2D_ELEMS;

    // chain (72.3 MB) in d_ws; f16 weights (31 MB) at the START of the x2d
    // region (b<4 rows). Helpers only assemble b>=4 rows; b<4 + rows 0..32
    // are written by assemble_fin after all weights are consumed.
    f16* chain = (f16*)d_ws;
    f16* Wf    = (f16*)x2d;

    prep_all<<<(30 * 262144) / 256, 256, 0, stream>>>(w1, w2, Wf, maskp);

    // layer 0: k=1 conv from fp32 x
    conv_first<<<dim3(8, 64), 256, 0, stream>>>(x, Wf, b1, chain);

    // level 0: 15 k=2 convs (64 -> 49); grid (8, 64), G=1, no helpers
    int L = 64, cb = 64, prev = 0, k2 = 0;
    for (int i = 0; i < 15; i++) {
        conv_k2<0><<<dim3(8, 64), 256, 0, stream>>>(
            prev, Wf + 262144 + (size_t)k2 * 524288, b2 + (size_t)k2 * C_,
            chain, 0, cb, L, L - 1, 1, 64, x2d, 0, 0, 0);
        k2++; prev = cb; cb += L - 1; L--;
    }
    // L=49, prev=855, cb=904

    // level 1: fused pool(49->24)+conv then 6 convs; G=2, grid (8, 32+20);
    // helpers assemble rows 47..63 (b>=4): 1020 units, 160/dispatch
    conv_k2<1><<<dim3(8, 52), 256, 0, stream>>>(
        prev, Wf + 262144 + (size_t)k2 * 524288, b2 + (size_t)k2 * C_,
        chain, 904, 928, 24, 23, 2, 32, x2d, 0, 1020, 47);
    k2++; L = 23; prev = 928; cb = 951;
    for (int i = 0; i < 6; i++) {
        conv_k2<0><<<dim3(8, 52), 256, 0, stream>>>(
            prev, Wf + 262144 + (size_t)k2 * 524288, b2 + (size_t)k2 * C_,
            chain, 0, cb, L, L - 1, 2, 32, x2d, (i + 1) * 160, 1020, 47);
        k2++; prev = cb; cb += L - 1; L--;
    }
    // L=17, prev=1051, cb=1068

    // level 2: fused pool(17->8)+conv then 6 convs; G=8, grid (8, 8+16);
    // helpers assemble rows 33..46 (b>=4): 840 units, 128/dispatch
    conv_k2<1><<<dim3(8, 24), 256, 0, stream>>>(
        prev, Wf + 262144 + (size_t)k2 * 524288, b2 + (size_t)k2 * C_,
        chain, 1068, 1076, 8, 7, 8, 8, x2d, 0, 840, 33);
    k2++; L = 7; prev = 1076; cb = 1083;
    for (int i = 0; i < 6; i++) {
        conv_k2<0><<<dim3(8, 24), 256, 0, stream>>>(
            prev, Wf + 262144 + (size_t)k2 * 524288, b2 + (size_t)k2 * C_,
            chain, 0, cb, L, L - 1, 8, 8, x2d, (i + 1) * 128, 840, 33);
        k2++; prev = cb; cb += L - 1; L--;
    }

    // final assemble: remaining 2236 units
    assemble_fin<<<2236, 256, 0, stream>>>(chain, x2d);
}